// Round 2
// baseline (266428.027 us; speedup 1.0000x reference)
//
#include <hip/hip_runtime.h>
#include <math.h>

// Problem constants
constexpr int NB = 32;     // batch
constexpr int NT = 512;    // time
constexpr int NH = 256;    // hidden
constexpr int NE = 256;    // embed
constexpr int NS = 50;     // scopes
constexpr int NV = 10000;  // vocab
constexpr int NWG = 256;   // workgroups in cooperative kernel
constexpr int BLK = 256;   // threads per workgroup
constexpr int NTH = NWG * BLK;

// NOTE: param names must not collide with float4 member names .x/.y/.z/.w
#define FMA4(acc, Wv, Xv) acc += (Wv).x*(Xv).x + (Wv).y*(Xv).y + (Wv).z*(Xv).z + (Wv).w*(Xv).w

struct Args {
  const int* tokens; const int* scope_idx; const int* is_id; const int* umask; const int* lengths;
  const float* emb;
  const float* w_ih0; const float* w_hh0; const float* b_ih0; const float* b_hh0;
  const float* w_ih1; const float* w_hh1; const float* b_ih1; const float* b_hh1;
  const float* st_w1; const float* st_b1; const float* st_w2; const float* st_b2;
  const float* gate_w; const float* gate_b; const float* val_w; const float* val_b;
  const float* h0; const float* c0;
  float* ws;
};

__device__ __forceinline__ float sigm(float x) { return 1.f / (1.f + __expf(-x)); }

// Grid-wide barrier: generation counter scheme, agent(device)-scope atomics.
// bar[0] = arrival counter (monotonic), bar[1] = generation.
__device__ __forceinline__ void grid_barrier(unsigned long long* bar) {
  __threadfence();   // release this thread's prior global writes
  __syncthreads();   // all threads of WG fenced before leader arrives
  if (threadIdx.x == 0) {
    unsigned long long g = __hip_atomic_load(bar + 1, __ATOMIC_RELAXED, __HIP_MEMORY_SCOPE_AGENT);
    unsigned long long arrive =
        __hip_atomic_fetch_add(bar, 1ULL, __ATOMIC_ACQ_REL, __HIP_MEMORY_SCOPE_AGENT) + 1ULL;
    if ((arrive % (unsigned long long)NWG) == 0ULL) {
      __hip_atomic_fetch_add(bar + 1, 1ULL, __ATOMIC_RELEASE, __HIP_MEMORY_SCOPE_AGENT);
    } else {
      while (__hip_atomic_load(bar + 1, __ATOMIC_ACQUIRE, __HIP_MEMORY_SCOPE_AGENT) == g) {
        __builtin_amdgcn_s_sleep(8);
      }
    }
  }
  __syncthreads();
  __threadfence();   // acquire side
}

__global__ __launch_bounds__(BLK) void rnn_kernel(Args a) {
  float* ws = a.ws;
  unsigned long long* bar = (unsigned long long*)ws;     // 16 floats reserved
  float* stack = ws + 16;                                // [NB][NS][NH]
  float* hbuf  = stack + NB * NS * NH;                   // [2 parity][2 layer][NB][NH]
  float* cbuf  = hbuf + 4 * NB * NH;                     // [2 layer][NB][NH]
  float* xin   = cbuf + 2 * NB * NH;                     // [NB][NH]
  float* feats = xin + NB * NH;                          // [NB][NT][NH]

  const int wg = blockIdx.x, tid = threadIdx.x;
  const int gt = wg * BLK + tid;

  // ---- init (every launch: graph replays must be self-contained)
  for (int i = gt; i < NB * NS * NH; i += NTH) stack[i] = 0.f;
  for (int i = gt; i < 2 * NB * NH; i += NTH) { hbuf[i] = a.h0[i]; cbuf[i] = a.c0[i]; }
  grid_barrier(bar);

  __shared__ __align__(16) float s_ns[NH];
  __shared__ __align__(16) float s_emb[NH];
  __shared__ __align__(16) float s_z[NH];
  __shared__ __align__(16) float s_out[NH];
  __shared__ __align__(16) float s_vp[NH];
  __shared__ __align__(16) float s_row[NH];
  __shared__ float s_gd, s_gte;

  for (int t = 0; t < NT; ++t) {
    const int p0 = t & 1, p1 = p0 ^ 1;

    // ================= P12: scope gather + MLP -> xin  (WG b = wg < 32)
    if (wg < NB) {
      const int b = wg;
      if (t < a.lengths[b]) {
        const int tok  = a.tokens[b * NT + t];
        const int sx   = a.scope_idx[b * NT + t];
        const int isid = a.is_id[b * NT + t];
        s_ns[tid]  = stack[(b * NS + sx) * NH + tid];
        s_emb[tid] = a.emb[tok * NE + tid];
        __syncthreads();
        // z[tid] = relu(st_w1[tid,:] . [ns; emb] + st_b1[tid])
        {
          float acc = a.st_b1[tid];
          const float4* w1r = (const float4*)(a.st_w1 + (size_t)tid * (NE + NH));
          const float4* nsv = (const float4*)s_ns;
          const float4* emv = (const float4*)s_emb;
          #pragma unroll 8
          for (int k = 0; k < NH / 4; ++k) { float4 wv = w1r[k]; float4 xv = nsv[k]; FMA4(acc, wv, xv); }
          #pragma unroll 8
          for (int k = 0; k < NE / 4; ++k) { float4 wv = w1r[NH / 4 + k]; float4 xv = emv[k]; FMA4(acc, wv, xv); }
          s_z[tid] = fmaxf(acc, 0.f);
        }
        __syncthreads();
        float xval;
        if (isid) {
          float acc = a.st_b2[tid];
          const float4* w2r = (const float4*)(a.st_w2 + (size_t)tid * NH);
          const float4* zv  = (const float4*)s_z;
          #pragma unroll 8
          for (int k = 0; k < NH / 4; ++k) { float4 wv = w2r[k]; float4 xv = zv[k]; FMA4(acc, wv, xv); }
          xval = acc;
        } else {
          xval = s_emb[tid];
        }
        xin[b * NH + tid] = xval;
      }
    }
    grid_barrier(bar);

    // ================= P3: LSTM layer 0 (item = b*1024 + jc*4 + gate)
    if (gt < NB * 4 * NH) {
      const int b = gt >> 10, r = gt & 1023, jc = r >> 2, g = r & 3;
      if (t < a.lengths[b]) {
        const int row = g * NH + jc;
        float acc = a.b_ih0[row] + a.b_hh0[row];
        const float4* wi = (const float4*)(a.w_ih0 + (size_t)row * NE);
        const float4* wh = (const float4*)(a.w_hh0 + (size_t)row * NH);
        const float4* xr = (const float4*)(xin + b * NH);
        const float4* hr = (const float4*)(hbuf + ((size_t)(p0 * 2 + 0) * NB + b) * NH);
        #pragma unroll 4
        for (int k = 0; k < NE / 4; ++k) { float4 wv = wi[k]; float4 xv = xr[k]; FMA4(acc, wv, xv); }
        #pragma unroll 4
        for (int k = 0; k < NH / 4; ++k) { float4 wv = wh[k]; float4 xv = hr[k]; FMA4(acc, wv, xv); }
        const float x1 = __shfl_xor(acc, 1, 64);
        const float x2 = __shfl_xor(acc, 2, 64);
        const float x3 = __shfl_xor(acc, 3, 64);
        if (g == 0) {  // lane has i; x1=f, x2=g, x3=o
          const int ci = (0 * NB + b) * NH + jc;
          const float c_ = sigm(x1) * cbuf[ci] + sigm(acc) * tanhf(x2);
          const float h_ = sigm(x3) * tanhf(c_);
          cbuf[ci] = c_;
          hbuf[((size_t)(p1 * 2 + 0) * NB + b) * NH + jc] = h_;
        }
      }
    }
    grid_barrier(bar);

    // ================= P4: LSTM layer 1 (input = new h0, recurrent = old h1)
    if (gt < NB * 4 * NH) {
      const int b = gt >> 10, r = gt & 1023, jc = r >> 2, g = r & 3;
      if (t < a.lengths[b]) {
        const int row = g * NH + jc;
        float acc = a.b_ih1[row] + a.b_hh1[row];
        const float4* wi = (const float4*)(a.w_ih1 + (size_t)row * NH);
        const float4* wh = (const float4*)(a.w_hh1 + (size_t)row * NH);
        const float4* xr = (const float4*)(hbuf + ((size_t)(p1 * 2 + 0) * NB + b) * NH);
        const float4* hr = (const float4*)(hbuf + ((size_t)(p0 * 2 + 1) * NB + b) * NH);
        #pragma unroll 4
        for (int k = 0; k < NH / 4; ++k) { float4 wv = wi[k]; float4 xv = xr[k]; FMA4(acc, wv, xv); }
        #pragma unroll 4
        for (int k = 0; k < NH / 4; ++k) { float4 wv = wh[k]; float4 xv = hr[k]; FMA4(acc, wv, xv); }
        const float x1 = __shfl_xor(acc, 1, 64);
        const float x2 = __shfl_xor(acc, 2, 64);
        const float x3 = __shfl_xor(acc, 3, 64);
        if (g == 0) {
          const int ci = (1 * NB + b) * NH + jc;
          const float c_ = sigm(x1) * cbuf[ci] + sigm(acc) * tanhf(x2);
          const float h_ = sigm(x3) * tanhf(c_);
          cbuf[ci] = c_;
          hbuf[((size_t)(p1 * 2 + 1) * NB + b) * NH + jc] = h_;
          feats[((size_t)b * NT + t) * NH + jc] = h_;
        }
      }
    }
    grid_barrier(bar);

    // ================= P6: stack update (8 WGs per b; WG sub handles ~6-7 slots)
    {
      const int b = wg >> 3, sub = wg & 7;
      if (t < a.lengths[b]) {
        const float* orow = hbuf + ((size_t)(p1 * 2 + 1) * NB + b) * NH;
        s_out[tid] = orow[tid];
        __syncthreads();
        // vproj[tid] = val_w[tid, H:] . out + val_b[tid]
        {
          float acc = a.val_b[tid];
          const float4* vr = (const float4*)(a.val_w + (size_t)tid * 2 * NH + NH);
          const float4* ov = (const float4*)s_out;
          #pragma unroll 8
          for (int k = 0; k < NH / 4; ++k) { float4 wv = vr[k]; float4 xv = ov[k]; FMA4(acc, wv, xv); }
          s_vp[tid] = acc;
        }
        if (tid < 64) {  // gdot = gate_w[H:] . out + gate_b  (wave-0 reduce)
          const float4 gw = ((const float4*)(a.gate_w + NH))[tid];
          const float4 xv = ((const float4*)s_out)[tid];
          float p = gw.x * xv.x + gw.y * xv.y + gw.z * xv.z + gw.w * xv.w;
          #pragma unroll
          for (int m = 1; m < 64; m <<= 1) p += __shfl_xor(p, m, 64);
          if (tid == 0) s_gd = p + a.gate_b[0];
        }
        __syncthreads();
        const int s0 = (NS * sub) / 8, s1v = (NS * (sub + 1)) / 8;
        for (int s = s0; s < s1v; ++s) {
          s_row[tid] = stack[(b * NS + s) * NH + tid];
          __syncthreads();
          if (tid < 64) {  // gate = sigmoid(gate_w[:H] . row + gdot)
            const float4 gw = ((const float4*)a.gate_w)[tid];
            const float4 xv = ((const float4*)s_row)[tid];
            float p = gw.x * xv.x + gw.y * xv.y + gw.z * xv.z + gw.w * xv.w;
            #pragma unroll
            for (int m = 1; m < 64; m <<= 1) p += __shfl_xor(p, m, 64);
            if (tid == 0) s_gte = sigm(p + s_gd);
          }
          __syncthreads();
          const float gte = s_gte;
          float vacc = s_vp[tid];
          const float4* vw = (const float4*)(a.val_w + (size_t)tid * 2 * NH);
          const float4* rw = (const float4*)s_row;
          #pragma unroll 8
          for (int k = 0; k < NH / 4; ++k) { float4 wv = vw[k]; float4 xv = rw[k]; FMA4(vacc, wv, xv); }
          const float val = tanhf(vacc);
          float ns = s_row[tid] * (1.f - gte) + gte * val;
          if (a.umask[((size_t)b * NT + t) * NS + s] > 0) ns = 0.f;
          __syncthreads();  // everyone done reading s_row before overwrite next iter
          stack[(b * NS + s) * NH + tid] = ns;
        }
      }
    }
    grid_barrier(bar);
  }
}

// ===================== logits epilogue =====================
constexpr int TB = 32;  // time rows per block
__global__ __launch_bounds__(256) void logits_kernel(
    const float* __restrict__ feats, const float* __restrict__ w1, const float* __restrict__ b1,
    const float* __restrict__ w2, const float* __restrict__ b2,
    const int* __restrict__ lengths, float* __restrict__ out) {
  const int blk = blockIdx.x;
  const int b = blk >> 4;            // 16 tiles of 32 rows per batch
  const int t0 = (blk & 15) * TB;
  const int tid = threadIdx.x;
  const int len = lengths[b];
  __shared__ __align__(16) float s_hid[TB][NH];

  for (int r = 0; r < TB; ++r) {
    const int t = t0 + r;
    float hv = 0.f;
    if (t < len) {
      const float4* fr = (const float4*)(feats + ((size_t)b * NT + t) * NH);
      const float4* wr = (const float4*)(w1 + (size_t)tid * NH);
      float acc = b1[tid];
      #pragma unroll 8
      for (int k = 0; k < NH / 4; ++k) { float4 wv = wr[k]; float4 fv = fr[k]; FMA4(acc, wv, fv); }
      hv = fmaxf(acc, 0.f);
    }
    s_hid[r][tid] = hv;
  }
  __syncthreads();

  // PAD rows -> -1.0
  for (int r = 0; r < TB; ++r) {
    const int t = t0 + r;
    if (t >= len) {
      float4* orow = (float4*)(out + ((size_t)b * NT + t) * NV);
      const float4 m1 = make_float4(-1.f, -1.f, -1.f, -1.f);
      for (int i = tid; i < NV / 4; i += 256) orow[i] = m1;
    }
  }
  if (t0 >= len) return;

  for (int pass = 0; pass < (NV + 511) / 512; ++pass) {
    const int v0 = pass * 512 + tid * 2;
    if (v0 >= NV) continue;
    float acc0[TB], acc1[TB];
    #pragma unroll
    for (int r = 0; r < TB; ++r) { acc0[r] = 0.f; acc1[r] = 0.f; }
    const float4* wa = (const float4*)(w2 + (size_t)v0 * NH);
    const float4* wb = (const float4*)(w2 + (size_t)(v0 + 1) * NH);
    for (int k = 0; k < NH / 4; ++k) {
      const float4 w0 = wa[k], w1v = wb[k];
      #pragma unroll
      for (int r = 0; r < TB; ++r) {
        const float4 hx = *(const float4*)&s_hid[r][k * 4];  // broadcast read
        acc0[r] += w0.x * hx.x + w0.y * hx.y + w0.z * hx.z + w0.w * hx.w;
        acc1[r] += w1v.x * hx.x + w1v.y * hx.y + w1v.z * hx.z + w1v.w * hx.w;
      }
    }
    const float bb0 = b2[v0], bb1 = b2[v0 + 1];
    for (int r = 0; r < TB; ++r) {
      const int t = t0 + r;
      if (t < len) {
        float2 st = make_float2(acc0[r] + bb0, acc1[r] + bb1);
        *(float2*)(out + ((size_t)b * NT + t) * NV + v0) = st;
      }
    }
  }
}

extern "C" void kernel_launch(void* const* d_in, const int* in_sizes, int n_in,
                              void* d_out, int out_size, void* d_ws, size_t ws_size,
                              hipStream_t stream) {
  (void)in_sizes; (void)n_in; (void)out_size; (void)ws_size;
  Args a;
  a.tokens    = (const int*)d_in[0];
  a.scope_idx = (const int*)d_in[1];
  a.is_id     = (const int*)d_in[2];
  a.umask     = (const int*)d_in[3];
  a.lengths   = (const int*)d_in[4];
  a.emb   = (const float*)d_in[5];
  a.w_ih0 = (const float*)d_in[6];  a.w_hh0 = (const float*)d_in[7];
  a.b_ih0 = (const float*)d_in[8];  a.b_hh0 = (const float*)d_in[9];
  a.w_ih1 = (const float*)d_in[10]; a.w_hh1 = (const float*)d_in[11];
  a.b_ih1 = (const float*)d_in[12]; a.b_hh1 = (const float*)d_in[13];
  a.st_w1 = (const float*)d_in[14]; a.st_b1 = (const float*)d_in[15];
  a.st_w2 = (const float*)d_in[16]; a.st_b2 = (const float*)d_in[17];
  a.gate_w = (const float*)d_in[18]; a.gate_b = (const float*)d_in[19];
  a.val_w  = (const float*)d_in[20]; a.val_b  = (const float*)d_in[21];
  const float* out_w1 = (const float*)d_in[22];
  const float* out_b1 = (const float*)d_in[23];
  const float* out_w2 = (const float*)d_in[24];
  const float* out_b2 = (const float*)d_in[25];
  a.h0 = (const float*)d_in[26];
  a.c0 = (const float*)d_in[27];
  a.ws = (float*)d_ws;

  // zero barrier state (each launch; graph-capturable)
  (void)hipMemsetAsync(d_ws, 0, 256, stream);

  void* kargs[] = { (void*)&a };
  hipError_t e = hipLaunchCooperativeKernel((const void*)rnn_kernel, dim3(NWG), dim3(BLK),
                                            kargs, 0, stream);
  if (e != hipSuccess) {
    // fallback: 256 WGs x 4 waves trivially co-resident on 256 CUs
    rnn_kernel<<<dim3(NWG), dim3(BLK), 0, stream>>>(a);
  }

  float* feats = (float*)d_ws + 16 + NB * NS * NH + 4 * NB * NH + 2 * NB * NH + NB * NH;
  logits_kernel<<<dim3(NB * (NT / TB)), dim3(256), 0, stream>>>(
      feats, out_w1, out_b1, out_w2, out_b2, a.lengths, (float*)d_out);
}

// Round 3
// 126098.096 us; speedup vs baseline: 2.1129x; 2.1129x over previous
//
#include <hip/hip_runtime.h>
#include <math.h>

// Problem constants
constexpr int NB = 32;     // batch
constexpr int NT = 512;    // time
constexpr int NH = 256;    // hidden
constexpr int NE = 256;    // embed
constexpr int NS = 50;     // scopes
constexpr int NV = 10000;  // vocab

// NOTE: param names must not collide with float4 member names .x/.y/.z/.w
#define FMA4(acc, Wv, Xv) acc += (Wv).x*(Xv).x + (Wv).y*(Xv).y + (Wv).z*(Xv).z + (Wv).w*(Xv).w

struct Args {
  const int* tokens; const int* scope_idx; const int* is_id; const int* umask; const int* lengths;
  const float* emb;
  const float* w_ih0; const float* w_hh0; const float* b_ih0; const float* b_hh0;
  const float* w_ih1; const float* w_hh1; const float* b_ih1; const float* b_hh1;
  const float* st_w1; const float* st_b1; const float* st_w2; const float* st_b2;
  const float* gate_w; const float* gate_b; const float* val_w; const float* val_b;
  const float* h0; const float* c0;
  float* ws;
};

__device__ __forceinline__ float sigm(float x) { return 1.f / (1.f + __expf(-x)); }

// One workgroup (1024 threads) per batch row. All recurrent state lives in LDS
// for the full T-scan; only __syncthreads() needed (batch rows are independent).
__global__ __launch_bounds__(1024) void rnn2_kernel(Args a) {
  const int b   = blockIdx.x;
  const int tid = threadIdx.x;
  const int len = a.lengths[b];
  float* feats  = a.ws;  // [NB][NT][NH]

  __shared__ __align__(16) float s_stk[2][NS][NH];   // 102.4 KB, parity double-buffer
  __shared__ __align__(16) float s_h[2][2][NH];      // [layer][parity][NH]
  __shared__ __align__(16) float s_c[2][NH];
  __shared__ __align__(16) float s_emb[NH];
  __shared__ __align__(16) float s_z[NH];
  __shared__ __align__(16) float s_xin[NH];
  __shared__ __align__(16) float s_vp[NH];
  __shared__ float s_gate[64];
  __shared__ float s_gd;

  // ---- init state in LDS
  for (int i = tid; i < NS * NH; i += 1024) s_stk[0][0][i] = 0.f;
  if (tid < NH) {
    s_h[0][0][tid] = a.h0[0 * NB * NH + b * NH + tid];
    s_h[1][0][tid] = a.h0[1 * NB * NH + b * NH + tid];
    s_c[0][tid]    = a.c0[0 * NB * NH + b * NH + tid];
    s_c[1][tid]    = a.c0[1 * NB * NH + b * NH + tid];
  }
  __syncthreads();

  for (int t = 0; t < len; ++t) {
    const int p0 = t & 1, p1 = p0 ^ 1;
    const int tok  = a.tokens[b * NT + t];
    const int sx   = a.scope_idx[b * NT + t];
    const int isid = a.is_id[b * NT + t];

    // ---- A: embedding row -> LDS
    if (tid < 64) ((float4*)s_emb)[tid] = ((const float4*)(a.emb + (size_t)tok * NE))[tid];
    __syncthreads();

    // ---- B: z = relu(st_w1 . [stack_row; emb] + st_b1)   (4 threads per output)
    {
      const int out = tid >> 2, part = tid & 3;
      const float4* wr = (const float4*)(a.st_w1 + (size_t)out * (NH + NE) + part * 128);
      const float4* xv4 = (part < 2) ? (const float4*)&s_stk[p0][sx][part * 128]
                                     : (const float4*)&s_emb[(part - 2) * 128];
      float acc = 0.f;
      #pragma unroll 8
      for (int k = 0; k < 32; ++k) { float4 wv = wr[k]; float4 xv = xv4[k]; FMA4(acc, wv, xv); }
      acc += __shfl_xor(acc, 1, 64);
      acc += __shfl_xor(acc, 2, 64);
      if (part == 0) s_z[out] = fmaxf(acc + a.st_b1[out], 0.f);
    }
    __syncthreads();

    // ---- C: xin = isid ? (st_w2 . z + st_b2) : emb
    if (isid) {
      const int out = tid >> 2, part = tid & 3;
      const float4* wr = (const float4*)(a.st_w2 + (size_t)out * NH + part * 64);
      const float4* zv4 = (const float4*)(s_z + part * 64);
      float acc = 0.f;
      #pragma unroll 8
      for (int k = 0; k < 16; ++k) { float4 wv = wr[k]; float4 xv = zv4[k]; FMA4(acc, wv, xv); }
      acc += __shfl_xor(acc, 1, 64);
      acc += __shfl_xor(acc, 2, 64);
      if (part == 0) s_xin[out] = acc + a.st_b2[out];
    } else {
      if (tid < 64) ((float4*)s_xin)[tid] = ((const float4*)s_emb)[tid];
    }
    __syncthreads();

    // ---- D: LSTM layer 0 (thread = gate g of cell jc; shfl gathers i,f,g,o)
    {
      const int jc = tid >> 2, g = tid & 3;
      const int row = g * NH + jc;
      float acc = a.b_ih0[row] + a.b_hh0[row];
      const float4* wi = (const float4*)(a.w_ih0 + (size_t)row * NE);
      const float4* wh = (const float4*)(a.w_hh0 + (size_t)row * NH);
      const float4* xr = (const float4*)s_xin;
      const float4* hr = (const float4*)s_h[0][p0];
      #pragma unroll 8
      for (int k = 0; k < 64; ++k) { float4 wv = wi[k]; float4 xv = xr[k]; FMA4(acc, wv, xv); }
      #pragma unroll 8
      for (int k = 0; k < 64; ++k) { float4 wv = wh[k]; float4 xv = hr[k]; FMA4(acc, wv, xv); }
      const float x1 = __shfl_xor(acc, 1, 64);
      const float x2 = __shfl_xor(acc, 2, 64);
      const float x3 = __shfl_xor(acc, 3, 64);
      if (g == 0) {
        const float c_ = sigm(x1) * s_c[0][jc] + sigm(acc) * tanhf(x2);
        s_c[0][jc] = c_;
        s_h[0][p1][jc] = sigm(x3) * tanhf(c_);
      }
    }
    __syncthreads();

    // ---- E: LSTM layer 1 (input = new h0, recurrent = old h1)
    {
      const int jc = tid >> 2, g = tid & 3;
      const int row = g * NH + jc;
      float acc = a.b_ih1[row] + a.b_hh1[row];
      const float4* wi = (const float4*)(a.w_ih1 + (size_t)row * NH);
      const float4* wh = (const float4*)(a.w_hh1 + (size_t)row * NH);
      const float4* xr = (const float4*)s_h[0][p1];
      const float4* hr = (const float4*)s_h[1][p0];
      #pragma unroll 8
      for (int k = 0; k < 64; ++k) { float4 wv = wi[k]; float4 xv = xr[k]; FMA4(acc, wv, xv); }
      #pragma unroll 8
      for (int k = 0; k < 64; ++k) { float4 wv = wh[k]; float4 xv = hr[k]; FMA4(acc, wv, xv); }
      const float x1 = __shfl_xor(acc, 1, 64);
      const float x2 = __shfl_xor(acc, 2, 64);
      const float x3 = __shfl_xor(acc, 3, 64);
      if (g == 0) {
        const float c_ = sigm(x1) * s_c[1][jc] + sigm(acc) * tanhf(x2);
        s_c[1][jc] = c_;
        s_h[1][p1][jc] = sigm(x3) * tanhf(c_);
      }
    }
    __syncthreads();

    // ---- F1: vproj = val_w[:, H:] . out + val_b   (4 threads per output)
    {
      const int out = tid >> 2, part = tid & 3;
      const float4* wr = (const float4*)(a.val_w + (size_t)out * 2 * NH + NH + part * 64);
      const float4* ov = (const float4*)(s_h[1][p1] + part * 64);
      float acc = 0.f;
      #pragma unroll 8
      for (int k = 0; k < 16; ++k) { float4 wv = wr[k]; float4 xv = ov[k]; FMA4(acc, wv, xv); }
      acc += __shfl_xor(acc, 1, 64);
      acc += __shfl_xor(acc, 2, 64);
      if (part == 0) s_vp[out] = acc + a.val_b[out];
    }
    __syncthreads();

    // ---- F2: wave0 -> gdot; wave1 -> store feats
    if (tid < 64) {
      const float4 gw = ((const float4*)(a.gate_w + NH))[tid];
      const float4 xv = ((const float4*)s_h[1][p1])[tid];
      float p = gw.x * xv.x + gw.y * xv.y + gw.z * xv.z + gw.w * xv.w;
      #pragma unroll
      for (int m = 1; m < 64; m <<= 1) p += __shfl_xor(p, m, 64);
      if (tid == 0) s_gd = p + a.gate_b[0];
    } else if (tid < 128) {
      const int l = tid - 64;
      ((float4*)(feats + ((size_t)b * NT + t) * NH))[l] = ((const float4*)s_h[1][p1])[l];
    }
    __syncthreads();

    // ---- F3: per-slot gate scalars (one wave per slot, round robin)
    {
      const int w = tid >> 6, l = tid & 63;
      const float4 gw = ((const float4*)a.gate_w)[l];
      for (int s = w; s < NS; s += 16) {
        const float4 xv = ((const float4*)s_stk[p0][s])[l];
        float p = gw.x * xv.x + gw.y * xv.y + gw.z * xv.z + gw.w * xv.w;
        #pragma unroll
        for (int m = 1; m < 64; m <<= 1) p += __shfl_xor(p, m, 64);
        if (l == 0) s_gate[s] = sigm(p + s_gd);
      }
    }
    __syncthreads();

    // ---- F4: val GEMM + gated stack update -> parity p1 (4 slots per thread/pass)
    {
      const int h = tid & 255, sg = tid >> 8;
      const float4* wr = (const float4*)(a.val_w + (size_t)h * 2 * NH);  // row h, [:H]
      const size_t ub = ((size_t)b * NT + t) * NS;
      for (int s0 = sg * 4; s0 < NS; s0 += 16) {
        const int n = (NS - s0 < 4) ? (NS - s0) : 4;
        float a0 = s_vp[h], a1 = a0, a2 = a0, a3 = a0;
        const float4* r0 = (const float4*)s_stk[p0][s0];
        const float4* r1 = (const float4*)s_stk[p0][(s0 + 1 < NS) ? s0 + 1 : s0];
        const float4* r2 = (const float4*)s_stk[p0][(s0 + 2 < NS) ? s0 + 2 : s0];
        const float4* r3 = (const float4*)s_stk[p0][(s0 + 3 < NS) ? s0 + 3 : s0];
        #pragma unroll 8
        for (int k = 0; k < 64; ++k) {
          const float4 wv = wr[k];
          float4 xv;
          xv = r0[k]; FMA4(a0, wv, xv);
          xv = r1[k]; FMA4(a1, wv, xv);
          xv = r2[k]; FMA4(a2, wv, xv);
          xv = r3[k]; FMA4(a3, wv, xv);
        }
        float accs[4] = { a0, a1, a2, a3 };
        #pragma unroll
        for (int j = 0; j < 4; ++j) {
          if (j < n) {
            const int s = s0 + j;
            const float gte = s_gate[s];
            const float val = tanhf(accs[j]);
            float ns = s_stk[p0][s][h] * (1.f - gte) + gte * val;
            if (a.umask[ub + s] > 0) ns = 0.f;
            s_stk[p1][s][h] = ns;
          }
        }
      }
    }
    __syncthreads();
  }
}

// ===================== logits epilogue =====================
constexpr int TB = 32;  // time rows per block
__global__ __launch_bounds__(256) void logits_kernel(
    const float* __restrict__ feats, const float* __restrict__ w1, const float* __restrict__ b1,
    const float* __restrict__ w2, const float* __restrict__ b2,
    const int* __restrict__ lengths, float* __restrict__ out) {
  const int blk = blockIdx.x;
  const int b = blk >> 4;            // 16 tiles of 32 rows per batch
  const int t0 = (blk & 15) * TB;
  const int tid = threadIdx.x;
  const int len = lengths[b];
  __shared__ __align__(16) float s_hid[TB][NH];

  for (int r = 0; r < TB; ++r) {
    const int t = t0 + r;
    float hv = 0.f;
    if (t < len) {
      const float4* fr = (const float4*)(feats + ((size_t)b * NT + t) * NH);
      const float4* wr = (const float4*)(w1 + (size_t)tid * NH);
      float acc = b1[tid];
      #pragma unroll 8
      for (int k = 0; k < NH / 4; ++k) { float4 wv = wr[k]; float4 fv = fr[k]; FMA4(acc, wv, fv); }
      hv = fmaxf(acc, 0.f);
    }
    s_hid[r][tid] = hv;
  }
  __syncthreads();

  // PAD rows -> -1.0
  for (int r = 0; r < TB; ++r) {
    const int t = t0 + r;
    if (t >= len) {
      float4* orow = (float4*)(out + ((size_t)b * NT + t) * NV);
      const float4 m1 = make_float4(-1.f, -1.f, -1.f, -1.f);
      for (int i = tid; i < NV / 4; i += 256) orow[i] = m1;
    }
  }
  if (t0 >= len) return;

  for (int pass = 0; pass < (NV + 511) / 512; ++pass) {
    const int v0 = pass * 512 + tid * 2;
    if (v0 >= NV) continue;
    float acc0[TB], acc1[TB];
    #pragma unroll
    for (int r = 0; r < TB; ++r) { acc0[r] = 0.f; acc1[r] = 0.f; }
    const float4* wa = (const float4*)(w2 + (size_t)v0 * NH);
    const float4* wb = (const float4*)(w2 + (size_t)(v0 + 1) * NH);
    for (int k = 0; k < NH / 4; ++k) {
      const float4 w0 = wa[k], w1v = wb[k];
      #pragma unroll
      for (int r = 0; r < TB; ++r) {
        const float4 hx = *(const float4*)&s_hid[r][k * 4];  // broadcast read
        acc0[r] += w0.x * hx.x + w0.y * hx.y + w0.z * hx.z + w0.w * hx.w;
        acc1[r] += w1v.x * hx.x + w1v.y * hx.y + w1v.z * hx.z + w1v.w * hx.w;
      }
    }
    const float bb0 = b2[v0], bb1 = b2[v0 + 1];
    for (int r = 0; r < TB; ++r) {
      const int t = t0 + r;
      if (t < len) {
        float2 st = make_float2(acc0[r] + bb0, acc1[r] + bb1);
        *(float2*)(out + ((size_t)b * NT + t) * NV + v0) = st;
      }
    }
  }
}

extern "C" void kernel_launch(void* const* d_in, const int* in_sizes, int n_in,
                              void* d_out, int out_size, void* d_ws, size_t ws_size,
                              hipStream_t stream) {
  (void)in_sizes; (void)n_in; (void)out_size; (void)ws_size;
  Args a;
  a.tokens    = (const int*)d_in[0];
  a.scope_idx = (const int*)d_in[1];
  a.is_id     = (const int*)d_in[2];
  a.umask     = (const int*)d_in[3];
  a.lengths   = (const int*)d_in[4];
  a.emb   = (const float*)d_in[5];
  a.w_ih0 = (const float*)d_in[6];  a.w_hh0 = (const float*)d_in[7];
  a.b_ih0 = (const float*)d_in[8];  a.b_hh0 = (const float*)d_in[9];
  a.w_ih1 = (const float*)d_in[10]; a.w_hh1 = (const float*)d_in[11];
  a.b_ih1 = (const float*)d_in[12]; a.b_hh1 = (const float*)d_in[13];
  a.st_w1 = (const float*)d_in[14]; a.st_b1 = (const float*)d_in[15];
  a.st_w2 = (const float*)d_in[16]; a.st_b2 = (const float*)d_in[17];
  a.gate_w = (const float*)d_in[18]; a.gate_b = (const float*)d_in[19];
  a.val_w  = (const float*)d_in[20]; a.val_b  = (const float*)d_in[21];
  const float* out_w1 = (const float*)d_in[22];
  const float* out_b1 = (const float*)d_in[23];
  const float* out_w2 = (const float*)d_in[24];
  const float* out_b2 = (const float*)d_in[25];
  a.h0 = (const float*)d_in[26];
  a.c0 = (const float*)d_in[27];
  a.ws = (float*)d_ws;

  rnn2_kernel<<<dim3(NB), dim3(1024), 0, stream>>>(a);

  float* feats = (float*)d_ws;
  logits_kernel<<<dim3(NB * (NT / TB)), dim3(256), 0, stream>>>(
      feats, out_w1, out_b1, out_w2, out_b2, a.lengths, (float*)d_out);
}

// Round 4
// 52457.452 us; speedup vs baseline: 5.0789x; 2.4038x over previous
//
#include <hip/hip_runtime.h>
#include <math.h>

// Problem constants
constexpr int NB = 32, NT = 512, NH = 256, NE = 256, NS = 50, NV = 10000;

typedef _Float16 h2 __attribute__((ext_vector_type(2)));
typedef _Float16 h4 __attribute__((ext_vector_type(4)));
typedef _Float16 h8 __attribute__((ext_vector_type(8)));

#define FMA4(acc, Wv, Xv) acc += (Wv).x*(Xv).x + (Wv).y*(Xv).y + (Wv).z*(Xv).z + (Wv).w*(Xv).w

#if __has_builtin(__builtin_amdgcn_fdot2)
__device__ __forceinline__ float dot2f(h2 a, h2 b, float c) { return __builtin_amdgcn_fdot2(a, b, c, false); }
#else
__device__ __forceinline__ float dot2f(h2 a, h2 b, float c) { return c + (float)a[0]*(float)b[0] + (float)a[1]*(float)b[1]; }
#endif

__device__ __forceinline__ float dot8(h8 w, h8 x, float acc) {
  const h2* wp = (const h2*)&w; const h2* xp = (const h2*)&x;
  acc = dot2f(wp[0], xp[0], acc); acc = dot2f(wp[1], xp[1], acc);
  acc = dot2f(wp[2], xp[2], acc); acc = dot2f(wp[3], xp[3], acc);
  return acc;
}

__device__ __forceinline__ float sigm(float x) { return 1.f / (1.f + __expf(-x)); }

// ---- f16 weight arena layout inside d_ws (offsets in halves) ----
constexpr size_t OFF_W0  = 0;        // [1024][512]  (w_ih0 row | w_hh0 row)
constexpr size_t OFF_W1  = 524288;   // [1024][512]
constexpr size_t OFF_SW1 = 1048576;  // [256][512]
constexpr size_t OFF_SW2 = 1179648;  // [256][256]
constexpr size_t OFF_VW  = 1245184;  // [256][512]  (cols 0..255 stack part, 256..511 out part)
constexpr size_t OFF_GW  = 1376256;  // [512]
constexpr size_t H_TOTAL = 1376768;
// fp32 region (offsets in floats from ws base)
constexpr size_t F_BC0   = H_TOTAL / 2;      // [1024] combined b_ih0+b_hh0
constexpr size_t F_BC1   = F_BC0 + 1024;     // [1024]

// ===================== weight cast / fuse prologue =====================
__global__ __launch_bounds__(256) void prep_kernel(
    const float* wih0, const float* whh0, const float* bih0, const float* bhh0,
    const float* wih1, const float* whh1, const float* bih1, const float* bhh1,
    const float* stw1, const float* stw2, const float* valw, const float* gatew,
    float* ws) {
  _Float16* hw = (_Float16*)ws;
  const int gt = blockIdx.x * blockDim.x + threadIdx.x;
  const int np = gridDim.x * blockDim.x;
  for (int i = gt; i < 1024 * 512; i += np) {
    const int r = i >> 9, c = i & 511;
    hw[OFF_W0 + i] = (_Float16)(c < 256 ? wih0[r * 256 + c] : whh0[r * 256 + c - 256]);
    hw[OFF_W1 + i] = (_Float16)(c < 256 ? wih1[r * 256 + c] : whh1[r * 256 + c - 256]);
  }
  for (int i = gt; i < 256 * 512; i += np) hw[OFF_SW1 + i] = (_Float16)stw1[i];
  for (int i = gt; i < 256 * 256; i += np) hw[OFF_SW2 + i] = (_Float16)stw2[i];
  for (int i = gt; i < 256 * 512; i += np) hw[OFF_VW + i]  = (_Float16)valw[i];
  for (int i = gt; i < 512; i += np)       hw[OFF_GW + i]  = (_Float16)gatew[i];
  for (int i = gt; i < 1024; i += np) {
    ws[F_BC0 + i] = bih0[i] + bhh0[i];
    ws[F_BC1 + i] = bih1[i] + bhh1[i];
  }
}

// ===================== recurrent scan: 1 WG (1024 thr) per batch row =====================
// feats are written into d_out[b][t][0:256] (reclaimed later by logits_kernel).
__global__ __launch_bounds__(1024) void rnn3_kernel(
    const int* __restrict__ tokens, const int* __restrict__ scope_idx,
    const int* __restrict__ is_id, const int* __restrict__ umask,
    const int* __restrict__ lengths, const float* __restrict__ emb,
    const float* __restrict__ stb1, const float* __restrict__ stb2,
    const float* __restrict__ gateb, const float* __restrict__ valb,
    const float* __restrict__ h0, const float* __restrict__ c0,
    const float* __restrict__ ws, float* __restrict__ out) {
  const int b = blockIdx.x, tid = threadIdx.x;
  const int len = lengths[b];
  const _Float16* hw = (const _Float16*)ws;
  const float* bc0 = ws + F_BC0;
  const float* bc1 = ws + F_BC1;

  __shared__ __align__(16) float    s_stk[NS][NH];    // fp32 truth, 51.2 KB, updated in place
  __shared__ __align__(16) _Float16 s_stkh[NS][NH];   // f16 shadow for dots, 25.6 KB
  __shared__ __align__(16) _Float16 s_xinh[NH];
  __shared__ __align__(16) _Float16 s_h0h[2][NH];
  __shared__ __align__(16) _Float16 s_h1h[2][NH];
  __shared__ __align__(16) _Float16 s_zh[NH];
  __shared__ __align__(16) _Float16 s_embh[NH];
  __shared__ __align__(16) float    s_c[2][NH];
  __shared__ __align__(16) float    s_out[NH];
  __shared__ __align__(16) float    s_vp[NH];
  __shared__ float s_gate[NS];     // sigmoid gate; <0 sentinel => zero the row (umask)
  __shared__ int   s_um[NS];

  // ---- init LDS state (self-contained per launch)
  for (int i = tid; i < NS * NH; i += 1024) { ((float*)s_stk)[i] = 0.f; ((_Float16*)s_stkh)[i] = (_Float16)0.f; }
  if (tid < NH) {
    s_h0h[0][tid] = (_Float16)h0[0 * NB * NH + b * NH + tid];
    s_h1h[0][tid] = (_Float16)h0[1 * NB * NH + b * NH + tid];
    s_c[0][tid] = c0[0 * NB * NH + b * NH + tid];
    s_c[1][tid] = c0[1 * NB * NH + b * NH + tid];
  }
  __syncthreads();

  for (int t = 0; t < len; ++t) {
    const int p0 = t & 1, p1 = p0 ^ 1;
    const int tok = tokens[b * NT + t], sx = scope_idx[b * NT + t], isid = is_id[b * NT + t];

    // ---- A: stage emb row (f16) + umask
    if (tid < 64) {
      const float4 e = ((const float4*)(emb + (size_t)tok * NE))[tid];
      h4 v = { (_Float16)e.x, (_Float16)e.y, (_Float16)e.z, (_Float16)e.w };
      ((h4*)s_embh)[tid] = v;
    } else if (tid >= 64 && tid < 64 + NS) {
      s_um[tid - 64] = umask[((size_t)b * NT + t) * NS + (tid - 64)];
    }
    __syncthreads();

    // ---- B: z = relu(st_w1 . [stack_row; emb] + st_b1)   (4 thr / output)
    {
      const int o = tid >> 2, part = tid & 3;
      const h8* wr = (const h8*)(hw + OFF_SW1 + (size_t)o * 512) + part * 16;
      const h8* xv = (part < 2) ? ((const h8*)s_stkh[sx]) + part * 16
                                : ((const h8*)s_embh) + (part - 2) * 16;
      float acc = 0.f;
      #pragma unroll
      for (int k = 0; k < 16; ++k) acc = dot8(wr[k], xv[k], acc);
      acc += __shfl_xor(acc, 1, 64); acc += __shfl_xor(acc, 2, 64);
      if (part == 0) s_zh[o] = (_Float16)fmaxf(acc + stb1[o], 0.f);
    }
    __syncthreads();

    // ---- C: xin = isid ? st_w2 . z + st_b2 : emb   (f16)
    if (isid) {
      const int o = tid >> 2, part = tid & 3;
      const h8* wr = (const h8*)(hw + OFF_SW2 + (size_t)o * 256) + part * 8;
      const h8* zv = ((const h8*)s_zh) + part * 8;
      float acc = 0.f;
      #pragma unroll
      for (int k = 0; k < 8; ++k) acc = dot8(wr[k], zv[k], acc);
      acc += __shfl_xor(acc, 1, 64); acc += __shfl_xor(acc, 2, 64);
      if (part == 0) s_xinh[o] = (_Float16)(acc + stb2[o]);
    } else if (tid < 64) {
      ((h4*)s_xinh)[tid] = ((const h4*)s_embh)[tid];
    }
    __syncthreads();

    // ---- D: LSTM layer 0 (thread = gate g of cell jc)
    {
      const int jc = tid >> 2, g = tid & 3, row = g * NH + jc;
      const h8* wr = (const h8*)(hw + OFF_W0) + (size_t)row * 64;
      const h8* xi = (const h8*)s_xinh;
      const h8* hp = (const h8*)s_h0h[p0];
      float acc = bc0[row];
      #pragma unroll 8
      for (int k = 0; k < 32; ++k) acc = dot8(wr[k], xi[k], acc);
      #pragma unroll 8
      for (int k = 0; k < 32; ++k) acc = dot8(wr[32 + k], hp[k], acc);
      const float x1 = __shfl_xor(acc, 1, 64);
      const float x2 = __shfl_xor(acc, 2, 64);
      const float x3 = __shfl_xor(acc, 3, 64);
      if (g == 0) {
        const float c_ = sigm(x1) * s_c[0][jc] + sigm(acc) * tanhf(x2);
        s_c[0][jc] = c_;
        s_h0h[p1][jc] = (_Float16)(sigm(x3) * tanhf(c_));
      }
    }
    __syncthreads();

    // ---- E: LSTM layer 1 (input = new h0, recurrent = old h1)
    {
      const int jc = tid >> 2, g = tid & 3, row = g * NH + jc;
      const h8* wr = (const h8*)(hw + OFF_W1) + (size_t)row * 64;
      const h8* xi = (const h8*)s_h0h[p1];
      const h8* hp = (const h8*)s_h1h[p0];
      float acc = bc1[row];
      #pragma unroll 8
      for (int k = 0; k < 32; ++k) acc = dot8(wr[k], xi[k], acc);
      #pragma unroll 8
      for (int k = 0; k < 32; ++k) acc = dot8(wr[32 + k], hp[k], acc);
      const float x1 = __shfl_xor(acc, 1, 64);
      const float x2 = __shfl_xor(acc, 2, 64);
      const float x3 = __shfl_xor(acc, 3, 64);
      if (g == 0) {
        const float c_ = sigm(x1) * s_c[1][jc] + sigm(acc) * tanhf(x2);
        s_c[1][jc] = c_;
        const float h_ = sigm(x3) * tanhf(c_);
        s_h1h[p1][jc] = (_Float16)h_;
        s_out[jc] = h_;
      }
    }
    __syncthreads();

    // ---- F: vproj (all threads) + feats store (wave 4) + per-slot gates (all waves)
    {
      const int o = tid >> 2, part = tid & 3;
      const h8* wr = (const h8*)(hw + OFF_VW + (size_t)o * 512 + 256) + part * 8;
      const h8* ov = ((const h8*)s_h1h[p1]) + part * 8;
      float acc = 0.f;
      #pragma unroll
      for (int k = 0; k < 8; ++k) acc = dot8(wr[k], ov[k], acc);
      acc += __shfl_xor(acc, 1, 64); acc += __shfl_xor(acc, 2, 64);
      if (part == 0) s_vp[o] = acc + valb[o];

      if (tid >= 256 && tid < 320) {  // feats -> out[b][t][0:256]
        const int l = tid - 256;
        ((float4*)(out + ((size_t)b * NT + t) * NV))[l] = ((const float4*)s_out)[l];
      }

      // slot gates: wave w handles slots w, w+16, w+32
      const int w = tid >> 6, l = tid & 63;
      const h2* gs  = (const h2*)(hw + OFF_GW);         // stack part
      const h2* go  = (const h2*)(hw + OFF_GW + 256);   // out part
      const h2* ovh = (const h2*)s_h1h[p1];
      float po = dot2f(go[2 * l], ovh[2 * l], 0.f);
      po = dot2f(go[2 * l + 1], ovh[2 * l + 1], po);
      for (int s = w; s < NS; s += 16) {
        const h2* rv = (const h2*)s_stkh[s];
        float p = dot2f(gs[2 * l], rv[2 * l], po);
        p = dot2f(gs[2 * l + 1], rv[2 * l + 1], p);
        #pragma unroll
        for (int m = 1; m < 64; m <<= 1) p += __shfl_xor(p, m, 64);
        if (l == 0) s_gate[s] = (s_um[s] > 0) ? -1.f : sigm(p + gateb[0]);
      }
    }
    __syncthreads();

    // ---- F4: val GEMM over all 50 slots, single pass over val_w[:, :H]
    {
      const int h = tid & 255, sg = tid >> 8;
      const int s0 = sg * 13;  // sg 0..2: 13 slots; sg 3: 11 slots
      const h8* wr = (const h8*)(hw + OFF_VW + (size_t)h * 512);  // stack-part chunks
      float acc[13];
      #pragma unroll
      for (int j = 0; j < 13; ++j) acc[j] = s_vp[h];
      #pragma unroll 2
      for (int k = 0; k < 32; ++k) {
        const h8 wv = wr[k];
        #pragma unroll
        for (int j = 0; j < 13; ++j) {
          const int s = (s0 + j < NS) ? s0 + j : NS - 1;
          acc[j] = dot8(wv, ((const h8*)s_stkh[s])[k], acc[j]);
        }
      }
      __syncthreads();  // all stack reads (B, F-gates, F4 dots) complete before writes
      #pragma unroll
      for (int j = 0; j < 13; ++j) {
        const int s = s0 + j;
        if (s < NS) {
          const float gv = s_gate[s];
          float ns;
          if (gv < 0.f) ns = 0.f;
          else          ns = s_stk[s][h] * (1.f - gv) + gv * tanhf(acc[j]);
          s_stk[s][h] = ns;
          s_stkh[s][h] = (_Float16)ns;
        }
      }
    }
    __syncthreads();
  }
}

// ===================== logits epilogue (feats live in out[b][t][0:256]) =====================
constexpr int TBR = 32;
__global__ __launch_bounds__(256) void logits_kernel(
    const float* __restrict__ w1, const float* __restrict__ b1,
    const float* __restrict__ w2, const float* __restrict__ b2,
    const int* __restrict__ lengths, float* __restrict__ out) {
  const int blk = blockIdx.x;
  const int b = blk >> 4;
  const int t0 = (blk & 15) * TBR;
  const int tid = threadIdx.x;
  const int len = lengths[b];
  __shared__ __align__(16) float s_fe[TBR][NH];
  __shared__ __align__(16) float s_hid[TBR][NH];

  // stage feats BEFORE this block overwrites its output rows
  for (int r = 0; r < TBR; ++r) {
    const int t = t0 + r;
    s_fe[r][tid] = (t < len) ? out[((size_t)b * NT + t) * NV + tid] : 0.f;
  }
  __syncthreads();

  for (int r = 0; r < TBR; ++r) {
    float acc = b1[tid];
    const float4* fr = (const float4*)s_fe[r];
    const float4* wr = (const float4*)(w1 + (size_t)tid * NH);
    #pragma unroll 8
    for (int k = 0; k < NH / 4; ++k) { float4 wv = wr[k]; float4 fv = fr[k]; FMA4(acc, wv, fv); }
    s_hid[r][tid] = fmaxf(acc, 0.f);
  }
  __syncthreads();

  // PAD rows -> -1.0
  for (int r = 0; r < TBR; ++r) {
    const int t = t0 + r;
    if (t >= len) {
      float4* orow = (float4*)(out + ((size_t)b * NT + t) * NV);
      const float4 m1 = make_float4(-1.f, -1.f, -1.f, -1.f);
      for (int i = tid; i < NV / 4; i += 256) orow[i] = m1;
    }
  }
  if (t0 >= len) return;

  for (int pass = 0; pass < (NV + 511) / 512; ++pass) {
    const int v0 = pass * 512 + tid * 2;
    if (v0 >= NV) continue;
    float acc0[TBR], acc1[TBR];
    #pragma unroll
    for (int r = 0; r < TBR; ++r) { acc0[r] = 0.f; acc1[r] = 0.f; }
    const float4* wa = (const float4*)(w2 + (size_t)v0 * NH);
    const float4* wb = (const float4*)(w2 + (size_t)(v0 + 1) * NH);
    for (int k = 0; k < NH / 4; ++k) {
      const float4 w0 = wa[k], w1v = wb[k];
      #pragma unroll
      for (int r = 0; r < TBR; ++r) {
        const float4 hx = *(const float4*)&s_hid[r][k * 4];
        acc0[r] += w0.x * hx.x + w0.y * hx.y + w0.z * hx.z + w0.w * hx.w;
        acc1[r] += w1v.x * hx.x + w1v.y * hx.y + w1v.z * hx.z + w1v.w * hx.w;
      }
    }
    const float bb0 = b2[v0], bb1 = b2[v0 + 1];
    for (int r = 0; r < TBR; ++r) {
      const int t = t0 + r;
      if (t < len) {
        float2 st = make_float2(acc0[r] + bb0, acc1[r] + bb1);
        *(float2*)(out + ((size_t)b * NT + t) * NV + v0) = st;
      }
    }
  }
}

extern "C" void kernel_launch(void* const* d_in, const int* in_sizes, int n_in,
                              void* d_out, int out_size, void* d_ws, size_t ws_size,
                              hipStream_t stream) {
  (void)in_sizes; (void)n_in; (void)out_size; (void)ws_size;
  const int* tokens    = (const int*)d_in[0];
  const int* scope_idx = (const int*)d_in[1];
  const int* is_id     = (const int*)d_in[2];
  const int* umask     = (const int*)d_in[3];
  const int* lengths   = (const int*)d_in[4];
  const float* emb   = (const float*)d_in[5];
  const float* wih0  = (const float*)d_in[6];  const float* whh0 = (const float*)d_in[7];
  const float* bih0  = (const float*)d_in[8];  const float* bhh0 = (const float*)d_in[9];
  const float* wih1  = (const float*)d_in[10]; const float* whh1 = (const float*)d_in[11];
  const float* bih1  = (const float*)d_in[12]; const float* bhh1 = (const float*)d_in[13];
  const float* stw1  = (const float*)d_in[14]; const float* stb1 = (const float*)d_in[15];
  const float* stw2  = (const float*)d_in[16]; const float* stb2 = (const float*)d_in[17];
  const float* gatew = (const float*)d_in[18]; const float* gateb = (const float*)d_in[19];
  const float* valw  = (const float*)d_in[20]; const float* valb  = (const float*)d_in[21];
  const float* outw1 = (const float*)d_in[22]; const float* outb1 = (const float*)d_in[23];
  const float* outw2 = (const float*)d_in[24]; const float* outb2 = (const float*)d_in[25];
  const float* h0 = (const float*)d_in[26];
  const float* c0 = (const float*)d_in[27];
  float* ws = (float*)d_ws;
  float* out = (float*)d_out;

  prep_kernel<<<dim3(256), dim3(256), 0, stream>>>(
      wih0, whh0, bih0, bhh0, wih1, whh1, bih1, bhh1, stw1, stw2, valw, gatew, ws);

  rnn3_kernel<<<dim3(NB), dim3(1024), 0, stream>>>(
      tokens, scope_idx, is_id, umask, lengths, emb,
      stb1, stb2, gateb, valb, h0, c0, ws, out);

  logits_kernel<<<dim3(NB * 16), dim3(256), 0, stream>>>(
      outw1, outb1, outw2, outb2, lengths, out);
}